// Round 5
// baseline (2588.647 us; speedup 1.0000x reference)
//
#include <hip/hip_runtime.h>
#include <hip/hip_bf16.h>
#include <math.h>

// ---------------- problem constants ----------------
#define N_INSTR   16384
#define T_TOK     16
#define N_BLOCKS  512
#define MAX_BLK   64
#define HDIM      128
#define P_INSTR   32
#define P_GLOB    8
#define D_WORD    296     // 2*H + P_INSTR + P_GLOB

#define CIB       32      // instructions per WG in char kernel

// per-parity h size: 2 dirs x 512 blocks x 128 units
#define HPAR      131072

__device__ __forceinline__ float sigf(float x) {
    return 1.0f / (1.0f + __expf(-x));
}
__device__ __forceinline__ float tanhf_s(float x) {
    float a = fabsf(x);
    float e = __expf(-2.0f * a);
    float t = (1.0f - e) / (1.0f + e);
    return copysignf(t, x);
}

// ---------------- weight packing ----------------
// Packed layout (float4 chunks over k): flat idx = ((k>>2)*NCOL + j)*4 + (k&3)
// charW4: NCOL=512, K=256 (k<128: Wih, k>=128: Whh)
// wordW4p: NCOL=1024 (j<512 fwd, else bwd), K=296 (Wih only)
// wordW4h: NCOL=1024, K=128 (Whh only)
__global__ __launch_bounds__(256) void prep_pack(
    const float* __restrict__ cWihF, const float* __restrict__ cWhhF,
    const float* __restrict__ cWihB, const float* __restrict__ cWhhB,
    const float* __restrict__ wWihF, const float* __restrict__ wWihB,
    const float* __restrict__ wWhhF, const float* __restrict__ wWhhB,
    float* __restrict__ W4cf, float* __restrict__ W4cb,
    float* __restrict__ W4p,  float* __restrict__ W4h)
{
    int idx = blockIdx.x * 256 + threadIdx.x;
    if (idx < 131072) {                       // char fwd
        int kk = idx & 3, f = idx >> 2;
        int j = f & 511, k = ((f >> 9) << 2) + kk;
        W4cf[idx] = (k < 128) ? cWihF[j*128 + k] : cWhhF[j*128 + (k-128)];
    } else if (idx < 262144) {                // char bwd
        int id = idx - 131072;
        int kk = id & 3, f = id >> 2;
        int j = f & 511, k = ((f >> 9) << 2) + kk;
        W4cb[id] = (k < 128) ? cWihB[j*128 + k] : cWhhB[j*128 + (k-128)];
    } else if (idx < 262144 + 303104) {       // word input proj (K=296, N=1024)
        int id = idx - 262144;
        int kk = id & 3, f = id >> 2;
        int j = f & 1023, k = ((f >> 10) << 2) + kk;
        W4p[id] = (j < 512) ? wWihF[j*296 + k] : wWihB[(j-512)*296 + k];
    } else if (idx < 565248 + 131072) {       // word recurrent (K=128, N=1024)
        int id = idx - 565248;
        int kk = id & 3, f = id >> 2;
        int j = f & 1023, k = ((f >> 10) << 2) + kk;
        W4h[id] = (j < 512) ? wWhhF[j*128 + k] : wWhhB[(j-512)*128 + k];
    }
}

// ---------------- block scan: starts + instruction->block id ----------------
__global__ __launch_bounds__(512) void scan_kernel(
    const int* __restrict__ block_lens, int* __restrict__ starts, int* __restrict__ bid)
{
    __shared__ int s[N_BLOCKS];
    int t = threadIdx.x;
    int len = block_lens[t];
    s[t] = len;
    __syncthreads();
    for (int off = 1; off < N_BLOCKS; off <<= 1) {
        int v = (t >= off) ? s[t - off] : 0;
        __syncthreads();
        s[t] += v;
        __syncthreads();
    }
    int start = s[t] - len;
    starts[t] = start;
    for (int p = 0; p < len; ++p) bid[start + p] = t;
}

__global__ __launch_bounds__(256) void zero_kernel(float4* __restrict__ p, int n4)
{
    int i = blockIdx.x * 256 + threadIdx.x;
    if (i < n4) p[i] = make_float4(0.f, 0.f, 0.f, 0.f);
}

// ---------------- char BiLSTM ----------------
// One WG = 32 instructions, 256 threads. Thread owns (unit u = tid&127,
// half = tid>>7 -> 16 instructions), all 4 gates. Full recurrence in-kernel.
__global__ __launch_bounds__(256, 2) void char_lstm(
    const int* __restrict__ tokens, const int* __restrict__ token_lens,
    const float* __restrict__ emb,
    const float* __restrict__ W4f, const float* __restrict__ W4b,
    const float* __restrict__ bf,  const float* __restrict__ bb,
    float* __restrict__ instr_h)
{
    __shared__ float inF[CIB][256];   // [x(128) | h(128)]
    __shared__ float inB[CIB][256];
    __shared__ int   toks[CIB][T_TOK];
    __shared__ int   lens[CIB];

    const int tid = threadIdx.x;
    const int i0  = blockIdx.x * CIB;

    for (int idx = tid; idx < CIB * T_TOK; idx += 256)
        toks[idx >> 4][idx & 15] = tokens[i0 * T_TOK + idx];
    if (tid < CIB) lens[tid] = token_lens[i0 + tid];
    for (int idx = tid; idx < CIB * 128; idx += 256) {
        inF[idx >> 7][128 + (idx & 127)] = 0.f;
        inB[idx >> 7][128 + (idx & 127)] = 0.f;
    }
    __syncthreads();

    const int u    = tid & 127;
    const int half = tid >> 7;
    const int ib0  = half * 16;

    float bfr[4], bbr[4];
    #pragma unroll
    for (int g = 0; g < 4; ++g) { bfr[g] = bf[g*128 + u]; bbr[g] = bb[g*128 + u]; }

    float cF[16], cB[16];
    #pragma unroll
    for (int i = 0; i < 16; ++i) { cF[i] = 0.f; cB[i] = 0.f; }

    const float4* Wf = (const float4*)W4f;
    const float4* Wb = (const float4*)W4b;

    for (int t = 0; t < T_TOK; ++t) {
        // fill x parts: 64 (dir,instr) combos, 4 threads each copy 32 float4
        {
            int combo = tid >> 2;
            int lane4 = tid & 3;
            int d = combo >> 5;
            int i = combo & 31;
            int len = lens[i];
            int tt = (d == 0) ? t : max(len - 1 - t, 0);
            const float4* src = (const float4*)(emb + toks[i][tt] * HDIM);
            float4* dst = (float4*)((d == 0) ? &inF[i][0] : &inB[i][0]);
            #pragma unroll
            for (int q = 0; q < 8; ++q) dst[lane4 + q*4] = src[lane4 + q*4];
        }
        __syncthreads();

        // ---------- forward ----------
        {
            float acc[16][4];
            #pragma unroll
            for (int i = 0; i < 16; ++i)
                { acc[i][0]=0.f; acc[i][1]=0.f; acc[i][2]=0.f; acc[i][3]=0.f; }
            for (int kc = 0; kc < 64; ++kc) {
                float4 w0 = Wf[kc*512 +   0 + u];
                float4 w1 = Wf[kc*512 + 128 + u];
                float4 w2 = Wf[kc*512 + 256 + u];
                float4 w3 = Wf[kc*512 + 384 + u];
                #pragma unroll
                for (int il = 0; il < 16; ++il) {
                    float4 x = *(const float4*)&inF[ib0 + il][kc*4];
                    acc[il][0] = fmaf(w0.x,x.x,fmaf(w0.y,x.y,fmaf(w0.z,x.z,fmaf(w0.w,x.w,acc[il][0]))));
                    acc[il][1] = fmaf(w1.x,x.x,fmaf(w1.y,x.y,fmaf(w1.z,x.z,fmaf(w1.w,x.w,acc[il][1]))));
                    acc[il][2] = fmaf(w2.x,x.x,fmaf(w2.y,x.y,fmaf(w2.z,x.z,fmaf(w2.w,x.w,acc[il][2]))));
                    acc[il][3] = fmaf(w3.x,x.x,fmaf(w3.y,x.y,fmaf(w3.z,x.z,fmaf(w3.w,x.w,acc[il][3]))));
                }
            }
            __syncthreads();     // all forward reads of inF done
            #pragma unroll
            for (int il = 0; il < 16; ++il) {
                int i = ib0 + il;
                if (t < lens[i]) {
                    float gi = sigf  (acc[il][0] + bfr[0]);
                    float gf = sigf  (acc[il][1] + bfr[1]);
                    float gg = tanhf_s(acc[il][2] + bfr[2]);
                    float go = sigf  (acc[il][3] + bfr[3]);
                    float cn = gf * cF[il] + gi * gg;
                    cF[il] = cn;
                    inF[i][128 + u] = go * tanhf_s(cn);
                }
            }
        }
        // ---------- backward ----------
        {
            float acc[16][4];
            #pragma unroll
            for (int i = 0; i < 16; ++i)
                { acc[i][0]=0.f; acc[i][1]=0.f; acc[i][2]=0.f; acc[i][3]=0.f; }
            for (int kc = 0; kc < 64; ++kc) {
                float4 w0 = Wb[kc*512 +   0 + u];
                float4 w1 = Wb[kc*512 + 128 + u];
                float4 w2 = Wb[kc*512 + 256 + u];
                float4 w3 = Wb[kc*512 + 384 + u];
                #pragma unroll
                for (int il = 0; il < 16; ++il) {
                    float4 x = *(const float4*)&inB[ib0 + il][kc*4];
                    acc[il][0] = fmaf(w0.x,x.x,fmaf(w0.y,x.y,fmaf(w0.z,x.z,fmaf(w0.w,x.w,acc[il][0]))));
                    acc[il][1] = fmaf(w1.x,x.x,fmaf(w1.y,x.y,fmaf(w1.z,x.z,fmaf(w1.w,x.w,acc[il][1]))));
                    acc[il][2] = fmaf(w2.x,x.x,fmaf(w2.y,x.y,fmaf(w2.z,x.z,fmaf(w2.w,x.w,acc[il][2]))));
                    acc[il][3] = fmaf(w3.x,x.x,fmaf(w3.y,x.y,fmaf(w3.z,x.z,fmaf(w3.w,x.w,acc[il][3]))));
                }
            }
            __syncthreads();     // all backward reads of inB done
            #pragma unroll
            for (int il = 0; il < 16; ++il) {
                int i = ib0 + il;
                if (t < lens[i]) {
                    float gi = sigf  (acc[il][0] + bbr[0]);
                    float gf = sigf  (acc[il][1] + bbr[1]);
                    float gg = tanhf_s(acc[il][2] + bbr[2]);
                    float go = sigf  (acc[il][3] + bbr[3]);
                    float cn = gf * cB[il] + gi * gg;
                    cB[il] = cn;
                    inB[i][128 + u] = go * tanhf_s(cn);
                }
            }
        }
        __syncthreads();         // h writes visible before next fill/k-loop
    }

    // write instr_h = [h_f | h_b]
    for (int idx = tid; idx < CIB * 128; idx += 256) {
        int i = idx >> 7, uu = idx & 127;
        instr_h[(i0 + i) * 256 +       uu] = inF[i][128 + uu];
        instr_h[(i0 + i) * 256 + 128 + uu] = inB[i][128 + uu];
    }
}

// ---------------- gather word inputs xw[i][296] ----------------
__global__ __launch_bounds__(256) void xw_gather(
    const float* __restrict__ instr_h, const float* __restrict__ instr_params,
    const float* __restrict__ gparams, const int* __restrict__ bid,
    float* __restrict__ xw)
{
    int idx = blockIdx.x * 256 + threadIdx.x;       // float4 index
    if (idx >= N_INSTR * 74) return;
    int i = idx / 74, c = idx % 74;
    float4 v;
    if (c < 64)      v = ((const float4*)(instr_h + i*256))[c];
    else if (c < 72) v = ((const float4*)(instr_params + i*32))[c - 64];
    else             v = ((const float4*)(gparams + bid[i]*8))[c - 72];
    ((float4*)(xw + i*296))[c] = v;
}

// ---------------- word input projection P[i][1024] = xw @ [WihF|WihB]^T + b ----------------
__global__ __launch_bounds__(256) void word_proj(
    const float* __restrict__ xw, const float* __restrict__ W4p,
    const float* __restrict__ b_f, const float* __restrict__ b_b,
    float* __restrict__ P)
{
    __shared__ float xs[16][296];
    int tid = threadIdx.x;
    int rowTile = blockIdx.x >> 2;
    int colTile = blockIdx.x & 3;
    int i0 = rowTile * 16;

    for (int idx = tid; idx < 16 * 74; idx += 256) {
        int i = idx / 74, c = idx % 74;
        ((float4*)&xs[i][0])[c] = ((const float4*)(xw + (size_t)(i0 + i) * 296))[c];
    }
    __syncthreads();

    int j = colTile * 256 + tid;
    float acc[16];
    #pragma unroll
    for (int i = 0; i < 16; ++i) acc[i] = 0.f;
    const float4* W4 = (const float4*)W4p;
    for (int kc = 0; kc < 74; ++kc) {
        float4 w = W4[kc*1024 + j];
        #pragma unroll
        for (int i = 0; i < 16; ++i) {
            float4 x = ((const float4*)&xs[i][0])[kc];
            acc[i] = fmaf(w.x,x.x,fmaf(w.y,x.y,fmaf(w.z,x.z,fmaf(w.w,x.w,acc[i]))));
        }
    }
    float bias = (j < 512) ? b_f[j] : b_b[j - 512];
    for (int i = 0; i < 16; ++i)
        P[(size_t)(i0 + i) * 1024 + j] = acc[i] + bias;
}

// ---------------- word recurrent step ----------------
// grid 128: bt = bx&15 (32-block tile), ut = (bx>>4)&3 (32-unit tile), d = bx>>6
// h double-buffered (ping-pong) with copy-through for masked blocks.
__global__ __launch_bounds__(256) void word_step(
    const float* __restrict__ W4h, const float* __restrict__ P,
    const int* __restrict__ starts, const int* __restrict__ block_lens,
    const float* __restrict__ hrd, float* __restrict__ hwr,
    float* __restrict__ cst, int t)
{
    __shared__ float hs[32][128];
    __shared__ int actflag;

    int bx = blockIdx.x;
    int bt = bx & 15, ut = (bx >> 4) & 3, d = bx >> 6;
    int tid = threadIdx.x;
    int b0 = bt * 32;

    const float* hbase = hrd + (size_t)(d * 512 + b0) * 128;
    for (int idx = tid; idx < 32 * 128 / 4; idx += 256)
        ((float4*)hs)[idx] = ((const float4*)hbase)[idx];
    if (tid == 0) actflag = 0;

    int u   = ut * 32 + (tid & 31);
    int bg  = tid >> 5;
    int lb0 = bg * 4;

    int blens[4], bsta[4], myact = 0;
    #pragma unroll
    for (int q = 0; q < 4; ++q) {
        int b = b0 + lb0 + q;
        blens[q] = block_lens[b];
        bsta[q]  = starts[b];
        myact |= (t < blens[q]) ? 1 : 0;
    }
    __syncthreads();
    if (myact) atomicOr(&actflag, 1);
    __syncthreads();

    float* hw = hwr + (size_t)(d * 512 + b0) * 128;
    if (!actflag) {  // whole tile inactive: copy-through our slice
        #pragma unroll
        for (int q = 0; q < 4; ++q) hw[(lb0 + q) * 128 + u] = hs[lb0 + q][u];
        return;
    }

    float acc[4][4];
    #pragma unroll
    for (int q = 0; q < 4; ++q)
        { acc[q][0]=0.f; acc[q][1]=0.f; acc[q][2]=0.f; acc[q][3]=0.f; }
    const float4* W4 = (const float4*)W4h;
    for (int kc = 0; kc < 32; ++kc) {
        float4 w0 = W4[kc*1024 + d*512 +   0 + u];
        float4 w1 = W4[kc*1024 + d*512 + 128 + u];
        float4 w2 = W4[kc*1024 + d*512 + 256 + u];
        float4 w3 = W4[kc*1024 + d*512 + 384 + u];
        #pragma unroll
        for (int q = 0; q < 4; ++q) {
            float4 h4 = *(const float4*)&hs[lb0 + q][kc*4];
            acc[q][0] = fmaf(w0.x,h4.x,fmaf(w0.y,h4.y,fmaf(w0.z,h4.z,fmaf(w0.w,h4.w,acc[q][0]))));
            acc[q][1] = fmaf(w1.x,h4.x,fmaf(w1.y,h4.y,fmaf(w1.z,h4.z,fmaf(w1.w,h4.w,acc[q][1]))));
            acc[q][2] = fmaf(w2.x,h4.x,fmaf(w2.y,h4.y,fmaf(w2.z,h4.z,fmaf(w2.w,h4.w,acc[q][2]))));
            acc[q][3] = fmaf(w3.x,h4.x,fmaf(w3.y,h4.y,fmaf(w3.z,h4.z,fmaf(w3.w,h4.w,acc[q][3]))));
        }
    }
    #pragma unroll
    for (int q = 0; q < 4; ++q) {
        int b = b0 + lb0 + q;
        int len = blens[q];
        float hold = hs[lb0 + q][u];
        if (t < len) {
            int rs = (d == 0) ? (bsta[q] + t) : (bsta[q] + len - 1 - t);
            const float* Prow = P + (size_t)rs * 1024 + d * 512;
            float g0 = acc[q][0] + Prow[  0 + u];
            float g1 = acc[q][1] + Prow[128 + u];
            float g2 = acc[q][2] + Prow[256 + u];
            float g3 = acc[q][3] + Prow[384 + u];
            float gi = sigf(g0), gf = sigf(g1), gg = tanhf_s(g2), go = sigf(g3);
            float* cp = cst + (size_t)(d * 512 + b) * 128 + u;
            float c  = *cp;
            float cn = gf * c + gi * gg;
            *cp = cn;
            hw[(lb0 + q) * 128 + u] = go * tanhf_s(cn);
        } else {
            hw[(lb0 + q) * 128 + u] = hold;
        }
    }
}

// ---------------- final linear ----------------
__global__ __launch_bounds__(256) void final_k(
    const float* __restrict__ hfinal, const float* __restrict__ gp,
    const float* __restrict__ fW, const float* __restrict__ fb,
    float* __restrict__ out)
{
    int tid = threadIdx.x;
    int w = tid >> 6, l = tid & 63;
    int b = blockIdx.x * 4 + w;
    const float* hf = hfinal + (size_t)(0 * 512 + b) * 128;
    const float* hb = hfinal + (size_t)(1 * 512 + b) * 128;
    float s = hf[l] * fW[l] + hf[l + 64] * fW[l + 64]
            + hb[l] * fW[128 + l] + hb[l + 64] * fW[192 + l];
    if (l < 8) s += gp[b * 8 + l] * fW[256 + l];
    #pragma unroll
    for (int off = 32; off > 0; off >>= 1) s += __shfl_down(s, off);
    if (l == 0) out[b] = s + fb[0];
}

// ---------------- launcher ----------------
extern "C" void kernel_launch(void* const* d_in, const int* in_sizes, int n_in,
                              void* d_out, int out_size, void* d_ws, size_t ws_size,
                              hipStream_t stream)
{
    const int*   tokens        = (const int*)  d_in[0];
    const int*   token_lens    = (const int*)  d_in[1];
    const int*   block_lens    = (const int*)  d_in[2];
    const float* instr_params  = (const float*)d_in[3];
    const float* global_params = (const float*)d_in[4];
    const float* emb           = (const float*)d_in[5];
    const float* cWihF = (const float*)d_in[6];
    const float* cWhhF = (const float*)d_in[7];
    const float* cbF   = (const float*)d_in[8];
    const float* cWihB = (const float*)d_in[9];
    const float* cWhhB = (const float*)d_in[10];
    const float* cbB   = (const float*)d_in[11];
    const float* wWihF = (const float*)d_in[12];
    const float* wWhhF = (const float*)d_in[13];
    const float* wbF   = (const float*)d_in[14];
    const float* wWihB = (const float*)d_in[15];
    const float* wWhhB = (const float*)d_in[16];
    const float* wbB   = (const float*)d_in[17];
    const float* fW    = (const float*)d_in[18];
    const float* fb    = (const float*)d_in[19];
    float* out = (float*)d_out;

    char* ws = (char*)d_ws;
    size_t off = 0;
    auto alloc_f = [&](size_t nfloats) { float* p = (float*)(ws + off); off += nfloats * 4; return p; };

    float* W4cf    = alloc_f(131072);
    float* W4cb    = alloc_f(131072);
    float* W4p     = alloc_f(303104);
    float* W4h     = alloc_f(131072);
    float* instr_h = alloc_f((size_t)N_INSTR * 256);
    float* xw      = alloc_f((size_t)N_INSTR * 296);
    float* P       = alloc_f((size_t)N_INSTR * 1024);
    float* hbuf    = alloc_f(2 * HPAR);             // 2 parities x (2 dirs x 512 x 128)
    float* cst     = alloc_f(2 * 512 * 128);        // contiguous after hbuf
    int*   starts  = (int*)(ws + off); off += 512 * 4;
    int*   bid     = (int*)(ws + off); off += N_INSTR * 4;

    prep_pack<<<2720, 256, 0, stream>>>(cWihF, cWhhF, cWihB, cWhhB,
                                        wWihF, wWihB, wWhhF, wWhhB,
                                        W4cf, W4cb, W4p, W4h);
    // zero hbuf (both parities) + cstate: 262144 + 131072 = 393216 floats = 98304 float4
    zero_kernel<<<384, 256, 0, stream>>>((float4*)hbuf, 98304);
    // scan AFTER zero so starts/bid can never be clobbered by the zero pass
    scan_kernel<<<1, 512, 0, stream>>>(block_lens, starts, bid);

    char_lstm<<<N_INSTR / CIB, 256, 0, stream>>>(tokens, token_lens, emb,
                                                 W4cf, W4cb, cbF, cbB, instr_h);
    xw_gather<<<4736, 256, 0, stream>>>(instr_h, instr_params, global_params, bid, xw);
    word_proj<<<4096, 256, 0, stream>>>(xw, W4p, wbF, wbB, P);

    for (int t = 0; t < MAX_BLK; ++t) {
        const float* hrd = hbuf + (size_t)(t & 1) * HPAR;
        float*       hwr = hbuf + (size_t)((t + 1) & 1) * HPAR;
        word_step<<<128, 256, 0, stream>>>(W4h, P, starts, block_lens, hrd, hwr, cst, t);
    }
    // final h is in parity 0 after t=63
    final_k<<<128, 256, 0, stream>>>(hbuf, global_params, fW, fb, out);
}